// Round 3
// baseline (6802.916 us; speedup 1.0000x reference)
//
#include <hip/hip_runtime.h>
#include <cstdint>

typedef unsigned long long u64;
typedef float f32x4 __attribute__((ext_vector_type(4)));
typedef short s16x4 __attribute__((ext_vector_type(4)));

#define Qn   515
#define QP   520          // padded cols of A
#define Bn   256
#define Tn   512
#define OQ   516
#define EPSc 1e-16f
#define NSL  65           // real cols per block slice
#define NT   5            // 16-wide n tiles per slice
#define KT   33           // k tiles over padded k space (528/16)
#define KTA  17           // split-K first chunk
#define QPW  528          // exchange words per row (8*66)
#define USTR 532          // ushorts per ustage row
#define NGRP 32
#define NBLK 8

// workspace layout (bytes)
#define WS_AMATH 0                          // 544*260*4 = 565,760 (bf16-pair packed A)
#define WS_INIT  565760                     // 520*4 -> pad 2560
#define WS_FBUF  568320                     // 2*NGRP*8*QPW*8 = 2,162,688 (fast, L2)
#define WS_SBUF  (WS_FBUF + 2162688)        // same size (slow, MALL)
#define WS_CAN   (WS_SBUF + 2162688)        // canary region
#define WS_TOTAL (WS_CAN + 4096)

// LDS layout (bytes)
#define L_FRAG 0
#define L_UST  (NT*KT*64*8)                 // 84,480
#define LDS_TOTAL (L_UST + 16*USTR*2 + 16)  // +17,024+16 = 101,520

__device__ __forceinline__ unsigned bfbits(float x) {
    unsigned u = __builtin_bit_cast(unsigned, x);
    unsigned r = u + 0x7FFFu + ((u >> 16) & 1u);
    return r >> 16;
}
__device__ __forceinline__ void l1_inv() {
    asm volatile("buffer_inv" ::: "memory");
}
__device__ __forceinline__ void exch_store(u64* f, u64* s, u64 v, bool dual) {
    __hip_atomic_store(f, v, __ATOMIC_RELAXED, __HIP_MEMORY_SCOPE_WORKGROUP); // plain -> local L2
    if (dual)
        __hip_atomic_store(s, v, __ATOMIC_RELAXED, __HIP_MEMORY_SCOPE_AGENT); // sc1 -> MALL
}

__global__ void prep_A(const float* __restrict__ logA, unsigned* __restrict__ AMATh) {
    __shared__ float red[4];
    __shared__ float srow[Qn];
    int row = blockIdx.x, tid = threadIdx.x;
    if (row >= Qn) {
        for (int c = tid; c < 260; c += 256) AMATh[(size_t)row*260 + c] = 0u;
        return;
    }
    float mx = -1e30f;
    for (int c = tid; c < Qn; c += 256) { float x = logA[(size_t)row*Qn + c]; srow[c] = x; mx = fmaxf(mx, x); }
#pragma unroll
    for (int o = 32; o > 0; o >>= 1) mx = fmaxf(mx, __shfl_xor(mx, o));
    if ((tid & 63) == 0) red[tid >> 6] = mx;
    __syncthreads();
    mx = fmaxf(fmaxf(red[0], red[1]), fmaxf(red[2], red[3]));
    __syncthreads();
    float sm = 0.f;
    for (int c = tid; c < Qn; c += 256) sm += __expf(srow[c] - mx);
#pragma unroll
    for (int o = 32; o > 0; o >>= 1) sm += __shfl_xor(sm, o);
    if ((tid & 63) == 0) red[tid >> 6] = sm;
    __syncthreads();
    float inv = 1.f / (red[0] + red[1] + red[2] + red[3]);
    for (int c2 = tid; c2 < 260; c2 += 256) {
        int c = 2*c2;
        float v0 = (c   < Qn) ? __expf(srow[c]   - mx) * inv : 0.f;
        float v1 = (c+1 < Qn) ? __expf(srow[c+1] - mx) * inv : 0.f;
        AMATh[(size_t)row*260 + c2] = bfbits(v0) | (bfbits(v1) << 16);
    }
}

__global__ void prep_init(const float* __restrict__ il, float* __restrict__ INITD) {
    __shared__ float red[4];
    __shared__ float srow[Qn];
    int tid = threadIdx.x;
    float mx = -1e30f;
    for (int c = tid; c < Qn; c += 256) { float x = il[c]; srow[c] = x; mx = fmaxf(mx, x); }
#pragma unroll
    for (int o = 32; o > 0; o >>= 1) mx = fmaxf(mx, __shfl_xor(mx, o));
    if ((tid & 63) == 0) red[tid >> 6] = mx;
    __syncthreads();
    mx = fmaxf(fmaxf(red[0], red[1]), fmaxf(red[2], red[3]));
    __syncthreads();
    float sm = 0.f;
    for (int c = tid; c < Qn; c += 256) sm += __expf(srow[c] - mx);
#pragma unroll
    for (int o = 32; o > 0; o >>= 1) sm += __shfl_xor(sm, o);
    if ((tid & 63) == 0) red[tid >> 6] = sm;
    __syncthreads();
    float inv = 1.f / (red[0] + red[1] + red[2] + red[3]);
    for (int c = tid; c < 520; c += 256)
        INITD[c] = (c < Qn) ? __expf(srow[c] - mx) * inv : 0.f;
}

__global__ void __launch_bounds__(256, 1)
hmm_fwd(const float* __restrict__ E, const unsigned* __restrict__ AMATh,
        const float* __restrict__ INITD, float* __restrict__ out,
        u64* __restrict__ fbuf, u64* __restrict__ sbuf,
        unsigned* __restrict__ can)
{
    extern __shared__ char smem[];
    uint2* frag = (uint2*)(smem + L_FRAG);                    // [NT*KT*64]
    unsigned short* ustage = (unsigned short*)(smem + L_UST); // [16][USTR]
    __shared__ unsigned modeflag;

    const int tid  = threadIdx.x;
    const int lane = tid & 63;
    const int wv   = tid >> 6;
    const int bid  = blockIdx.x;
    const int g    = bid & 31;
    const int j    = bid >> 5;
    const int b0   = g * 8;
    const int q0   = j * NSL;
    const int q0p  = j * 66;

    // ---- canary handshake: is my whole group L2-coherent (same XCD)? ----
    if (tid == 0) {
        unsigned slow = 0;
        unsigned* myc = &can[(unsigned)g*NBLK + j];
        for (int r = 0; r < 8 && !slow; ++r) {
            __hip_atomic_store(myc, (unsigned)(r+1), __ATOMIC_RELAXED, __HIP_MEMORY_SCOPE_WORKGROUP);
            long long limit = (r == 0) ? 8000000LL : 80000LL;
            long long t0 = __builtin_readcyclecounter();
            for (int p = 0; p < NBLK && !slow; ++p) {
                if (p == j) continue;
                while (true) {
                    l1_inv();
                    unsigned vv = __hip_atomic_load(&can[(unsigned)g*NBLK + p],
                                                    __ATOMIC_RELAXED, __HIP_MEMORY_SCOPE_WORKGROUP);
                    if (vv >= (unsigned)(r+1) && vv <= 8u) break;
                    if (__builtin_readcyclecounter() - t0 > limit) { slow = 1; break; }
                }
            }
        }
        modeflag = slow;
    }

    // ---- one-time: pack A column-slice into LDS as MFMA B-fragments ----
    for (int f = tid; f < NT*KT*64; f += 256) {
        int tile = f >> 6, l = f & 63;
        int nt = tile / KT, kt = tile - nt*KT;
        int col = q0 + nt*16 + (l & 15);
        int kb  = kt*16 + ((l >> 4) << 2);
        unsigned h[4];
#pragma unroll
        for (int i = 0; i < 4; ++i) {
            int pk_ = kb + i;
            int jr = pk_ / 66, rr = pk_ - jr*66;
            unsigned hv = 0;
            if (rr < 65 && col < QP) {
                int qrow = jr*65 + rr;
                unsigned w = AMATh[(size_t)qrow*260 + (col >> 1)];
                hv = (col & 1) ? (w >> 16) : (w & 0xffffu);
            }
            h[i] = hv;
        }
        uint2 pk;
        pk.x = h[0] | (h[1] << 16);
        pk.y = h[2] | (h[3] << 16);
        frag[f] = pk;
    }
    for (int i = tid; i < 16*(USTR/2); i += 256) ((unsigned*)ustage)[i] = 0u;
    __syncthreads();
    const bool slowmode = (modeflag != 0);

    // ---- per-thread maps ----
    const int ntn = (wv == 0) ? 2 : 1;
    const int nts0 = wv;
    int eoff[2][4];
#pragma unroll
    for (int sl = 0; sl < 2; ++sl) {
#pragma unroll
        for (int r = 0; r < 4; ++r) {
            int nt  = sl ? 4 : nts0;
            int row = ((lane >> 4) << 2) + r;
            int col = nt*16 + (lane & 15);
            int q   = q0 + col;
            bool ok = (lane < 32) && (col < NSL) && (q < Qn) && (sl < ntn);
            eoff[sl][r] = ok ? ((b0 + row)*Qn + q) : -1;
        }
    }
    const int rrow = tid >> 5;     // reader row 0..7
    const int t32  = tid & 31;

    float llreg = 0.f;
    float v[17];
    float lsr = 0.f;

    // ---- t = 0 ----
    {
        u64* fw = fbuf + ((size_t)0*NGRP + g)*8*QPW;
        u64* sw = sbuf + ((size_t)0*NGRP + g)*8*QPW;
        for (int p = tid; p < 8*66; p += 256) {
            int row = p / 66, c = p - row*66;
            int q = q0 + c;
            float uv = 0.f;
            if (c < 65 && q < Qn)
                uv = fmaxf(E[(size_t)(b0+row)*Qn + q], EPSc) * fmaxf(INITD[q], EPSc);
            u64 pk = (u64)__builtin_bit_cast(unsigned, uv) | ((u64)1u << 32);
            exch_store(&fw[(size_t)row*QPW + q0p + c], &sw[(size_t)row*QPW + q0p + c], pk, slowmode);
        }
    }

    auto poll_read = [&](int s) {   // read data of step s-1 (tag s) from slot (s-1)&1
        const size_t base = ((size_t)((s-1) & 1)*NGRP + g)*8*QPW + (size_t)rrow*QPW;
        const u64* fb = fbuf + base;
        const u64* sb = sbuf + base;
        unsigned want = (unsigned)s;
        u64 w[17];
        unsigned pend = (t32 < 16) ? 0x1FFFFu : 0xFFFFu;
        int iter = 0;
        while (true) {
            l1_inv();
            bool sp = slowmode && ((iter & 3) == 3);
#pragma unroll
            for (int k = 0; k < 17; ++k) {
                if (pend & (1u << k)) {
                    int pc = t32 + 32*k;
                    w[k] = sp ? __hip_atomic_load(&sb[pc], __ATOMIC_RELAXED, __HIP_MEMORY_SCOPE_AGENT)
                              : __hip_atomic_load(&fb[pc], __ATOMIC_RELAXED, __HIP_MEMORY_SCOPE_WORKGROUP);
                }
            }
#pragma unroll
            for (int k = 0; k < 17; ++k)
                if ((pend & (1u << k)) && (unsigned)(w[k] >> 32) == want) pend &= ~(1u << k);
            if (pend == 0) break;
            if (slowmode) __builtin_amdgcn_s_sleep(1);
            ++iter;
        }
        float sum = 0.f;
#pragma unroll
        for (int k = 0; k < 17; ++k) {
            int pc = t32 + 32*k;
            v[k] = (pc < QPW) ? __builtin_bit_cast(float, (unsigned)(w[k] & 0xffffffffu)) : 0.f;
            sum += v[k];
        }
#pragma unroll
        for (int o = 1; o < 32; o <<= 1) sum += __shfl_xor(sum, o);
        lsr = __logf(sum);
        llreg += lsr;
        return 1.f / sum;
    };

    auto emit_outputs = [&](int tOut) {
        if (j == 0 && t32 == 0)
            out[((size_t)(b0 + rrow)*Tn + tOut)*OQ + Qn] = llreg;
#pragma unroll
        for (int k = 0; k < 17; ++k) {
            int pc = t32 + 32*k;
            int c = pc - q0p;
            if (pc < QPW && c >= 0 && c < 65) {
                int q = q0 + c;
                if (q < Qn)
                    out[((size_t)(b0 + rrow)*Tn + tOut)*OQ + q] = __logf(v[k]) - lsr;
            }
        }
    };

    // ---- main loop ----
    for (int s = 1; s < Tn; ++s) {
        // prefetch E_s (latency hides under the poll)
        float ev[2][4];
        size_t ebase = (size_t)s * Bn * Qn;
#pragma unroll
        for (int sl = 0; sl < 2; ++sl)
#pragma unroll
            for (int r = 0; r < 4; ++r)
                ev[sl][r] = (eoff[sl][r] >= 0) ? E[ebase + eoff[sl][r]] : 0.f;

        float inv = poll_read(s);

        __syncthreads();   // all waves done with previous MFMA's ustage reads
#pragma unroll
        for (int k = 0; k < 17; ++k) {
            int pc = t32 + 32*k;
            if (pc < QPW)
                ustage[rrow*USTR + pc] = (unsigned short)bfbits(v[k] * inv);
        }
        __syncthreads();   // stage visible

        // MFMA: R = a_{s-1} (16xK, rows 8..15 zero) @ Aslice (KxN), split-K x2
        f32x4 a0a = {0.f,0.f,0.f,0.f}, a0b = {0.f,0.f,0.f,0.f};
        f32x4 a1a = {0.f,0.f,0.f,0.f}, a1b = {0.f,0.f,0.f,0.f};
        {
            const unsigned short* urow = ustage + (lane & 15)*USTR + ((lane >> 4) << 2);
            const uint2* f0 = frag + (size_t)(nts0*KT)*64 + lane;
            const uint2* f1 = frag + (size_t)(4*KT)*64 + lane;
#pragma unroll 2
            for (int kt = 0; kt < KTA; ++kt) {
                s16x4 af = __builtin_bit_cast(s16x4, *(const uint2*)(urow + kt*16));
                a0a = __builtin_amdgcn_mfma_f32_16x16x16bf16_1k(af, __builtin_bit_cast(s16x4, f0[kt*64]), a0a, 0, 0, 0);
                if (ntn == 2)
                    a1a = __builtin_amdgcn_mfma_f32_16x16x16bf16_1k(af, __builtin_bit_cast(s16x4, f1[kt*64]), a1a, 0, 0, 0);
                int k2 = kt + KTA;
                if (k2 < KT) {
                    s16x4 af2 = __builtin_bit_cast(s16x4, *(const uint2*)(urow + k2*16));
                    a0b = __builtin_amdgcn_mfma_f32_16x16x16bf16_1k(af2, __builtin_bit_cast(s16x4, f0[k2*64]), a0b, 0, 0, 0);
                    if (ntn == 2)
                        a1b = __builtin_amdgcn_mfma_f32_16x16x16bf16_1k(af2, __builtin_bit_cast(s16x4, f1[k2*64]), a1b, 0, 0, 0);
                }
            }
        }
        // epilogue: u_s = max(E,eps) * max(R,eps) -> direct exchange stores
        {
            unsigned seqv = (unsigned)(s + 1);
            size_t wbase = ((size_t)(s & 1)*NGRP + g)*8*QPW;
            u64* fw = fbuf + wbase;
            u64* sw = sbuf + wbase;
            if (lane < 32) {
#pragma unroll
                for (int r = 0; r < 4; ++r) {
                    int row = ((lane >> 4) << 2) + r;
                    {
                        int col = nts0*16 + (lane & 15);
                        float R = fmaxf(a0a[r] + a0b[r], EPSc);
                        int q = q0 + col;
                        float uv = (q < Qn) ? fmaxf(ev[0][r], EPSc) * R : 0.f;
                        u64 pk = (u64)__builtin_bit_cast(unsigned, uv) | ((u64)seqv << 32);
                        size_t off = (size_t)row*QPW + q0p + col;
                        exch_store(&fw[off], &sw[off], pk, slowmode);
                    }
                    if (ntn == 2 && (lane & 15) == 0) {
                        int col = 64;
                        float R = fmaxf(a1a[r] + a1b[r], EPSc);
                        int q = q0 + col;
                        float uv = (q < Qn) ? fmaxf(ev[1][r], EPSc) * R : 0.f;
                        u64 pk = (u64)__builtin_bit_cast(unsigned, uv) | ((u64)seqv << 32);
                        size_t off = (size_t)row*QPW + q0p + col;
                        exch_store(&fw[off], &sw[off], pk, slowmode);
                    }
                }
            }
            if (wv == 1 && lane >= 32 && lane < 40) {  // pad col 65 per row
                int row = lane - 32;
                u64 pk = ((u64)seqv << 32);
                size_t off = (size_t)row*QPW + q0p + 65;
                exch_store(&fw[off], &sw[off], pk, slowmode);
            }
        }
        // off the critical path: log-outputs for t = s-1
        emit_outputs(s - 1);
    }

    // ---- tail: t = 511 ----
    poll_read(Tn);
    emit_outputs(Tn - 1);
}

extern "C" void kernel_launch(void* const* d_in, const int* in_sizes, int n_in,
                              void* d_out, int out_size, void* d_ws, size_t ws_size,
                              hipStream_t stream) {
    (void)in_sizes; (void)n_in; (void)out_size;
    if (ws_size < (size_t)WS_TOTAL) return;

    const float* E    = (const float*)d_in[0];
    const float* logA = (const float*)d_in[1];
    const float* il   = (const float*)d_in[2];
    float* out = (float*)d_out;
    char*  ws  = (char*)d_ws;

    unsigned* AMATh = (unsigned*)(ws + WS_AMATH);
    float*    INITD = (float*)(ws + WS_INIT);
    u64*      fbuf  = (u64*)(ws + WS_FBUF);
    u64*      sbuf  = (u64*)(ws + WS_SBUF);
    unsigned* can   = (unsigned*)(ws + WS_CAN);

    // canaries must start at 0 every launch/replay (protocol depends on it)
    hipMemsetAsync(ws + WS_CAN, 0, 4096, stream);

    prep_A<<<544, 256, 0, stream>>>(logA, AMATh);
    prep_init<<<1, 256, 0, stream>>>(il, INITD);

    static_assert(LDS_TOTAL < 160*1024, "LDS budget");
    hipFuncSetAttribute(reinterpret_cast<const void*>(hmm_fwd),
                        hipFuncAttributeMaxDynamicSharedMemorySize, LDS_TOTAL);
    hmm_fwd<<<256, 256, LDS_TOTAL, stream>>>(E, AMATh, INITD, out, fbuf, sbuf, can);
}

// Round 4
// 2928.942 us; speedup vs baseline: 2.3227x; 2.3227x over previous
//
#include <hip/hip_runtime.h>
#include <cstdint>

typedef unsigned long long u64;
typedef float f32x4 __attribute__((ext_vector_type(4)));
typedef short s16x4 __attribute__((ext_vector_type(4)));

#define Qn   515
#define QP   520          // padded cols of A
#define Bn   256
#define Tn   512
#define OQ   516
#define EPSc 1e-16f
#define NSL  65           // real cols per block slice
#define NT   5            // 16-wide n tiles per slice
#define KT   33           // k tiles over padded k space (528/16)
#define KTA  17           // split-K first chunk
#define QPW  528          // exchange words per row (8*66)
#define USTR 532          // ushorts per ustage row (zero-conflict, measured r3)
#define NGRP 32
#define NBLK 8

// workspace layout (bytes)
#define WS_AMATH 0                          // 544*260*4 = 565,760 (bf16-pair packed A)
#define WS_INIT  565760                     // 520*4 -> pad 2560
#define WS_FBUF  568320                     // 2*NGRP*8*QPW*8 = 2,162,688
#define WS_TOTAL (WS_FBUF + 2162688)

// LDS layout (bytes)
#define L_FRAG 0
#define L_UST  (NT*KT*64*8)                 // 84,480
#define LDS_TOTAL (L_UST + 16*USTR*2 + 16)  // +17,024+16 = 101,520

__device__ __forceinline__ unsigned bfbits(float x) {
    unsigned u = __builtin_bit_cast(unsigned, x);
    unsigned r = u + 0x7FFFu + ((u >> 16) & 1u);
    return r >> 16;
}

__global__ void prep_A(const float* __restrict__ logA, unsigned* __restrict__ AMATh) {
    __shared__ float red[4];
    __shared__ float srow[Qn];
    int row = blockIdx.x, tid = threadIdx.x;
    if (row >= Qn) {
        for (int c = tid; c < 260; c += 256) AMATh[(size_t)row*260 + c] = 0u;
        return;
    }
    float mx = -1e30f;
    for (int c = tid; c < Qn; c += 256) { float x = logA[(size_t)row*Qn + c]; srow[c] = x; mx = fmaxf(mx, x); }
#pragma unroll
    for (int o = 32; o > 0; o >>= 1) mx = fmaxf(mx, __shfl_xor(mx, o));
    if ((tid & 63) == 0) red[tid >> 6] = mx;
    __syncthreads();
    mx = fmaxf(fmaxf(red[0], red[1]), fmaxf(red[2], red[3]));
    __syncthreads();
    float sm = 0.f;
    for (int c = tid; c < Qn; c += 256) sm += __expf(srow[c] - mx);
#pragma unroll
    for (int o = 32; o > 0; o >>= 1) sm += __shfl_xor(sm, o);
    if ((tid & 63) == 0) red[tid >> 6] = sm;
    __syncthreads();
    float inv = 1.f / (red[0] + red[1] + red[2] + red[3]);
    for (int c2 = tid; c2 < 260; c2 += 256) {
        int c = 2*c2;
        float v0 = (c   < Qn) ? __expf(srow[c]   - mx) * inv : 0.f;
        float v1 = (c+1 < Qn) ? __expf(srow[c+1] - mx) * inv : 0.f;
        AMATh[(size_t)row*260 + c2] = bfbits(v0) | (bfbits(v1) << 16);
    }
}

__global__ void prep_init(const float* __restrict__ il, float* __restrict__ INITD) {
    __shared__ float red[4];
    __shared__ float srow[Qn];
    int tid = threadIdx.x;
    float mx = -1e30f;
    for (int c = tid; c < Qn; c += 256) { float x = il[c]; srow[c] = x; mx = fmaxf(mx, x); }
#pragma unroll
    for (int o = 32; o > 0; o >>= 1) mx = fmaxf(mx, __shfl_xor(mx, o));
    if ((tid & 63) == 0) red[tid >> 6] = mx;
    __syncthreads();
    mx = fmaxf(fmaxf(red[0], red[1]), fmaxf(red[2], red[3]));
    __syncthreads();
    float sm = 0.f;
    for (int c = tid; c < Qn; c += 256) sm += __expf(srow[c] - mx);
#pragma unroll
    for (int o = 32; o > 0; o >>= 1) sm += __shfl_xor(sm, o);
    if ((tid & 63) == 0) red[tid >> 6] = sm;
    __syncthreads();
    float inv = 1.f / (red[0] + red[1] + red[2] + red[3]);
    for (int c = tid; c < 520; c += 256)
        INITD[c] = (c < Qn) ? __expf(srow[c] - mx) * inv : 0.f;
}

__global__ void __launch_bounds__(256, 1)
hmm_fwd(const float* __restrict__ E, const unsigned* __restrict__ AMATh,
        const float* __restrict__ INITD, float* __restrict__ out,
        u64* __restrict__ fbuf)
{
    extern __shared__ char smem[];
    uint2* frag = (uint2*)(smem + L_FRAG);                    // [NT*KT*64]
    unsigned short* ustage = (unsigned short*)(smem + L_UST); // [16][USTR]

    const int tid  = threadIdx.x;
    const int lane = tid & 63;
    const int wv   = tid >> 6;
    const int bid  = blockIdx.x;
    const int g    = bid & 31;
    const int j    = bid >> 5;
    const int b0   = g * 8;
    const int q0   = j * NSL;
    const int q0p  = j * 66;

    // ---- one-time: pack A column-slice into LDS as MFMA B-fragments ----
    for (int f = tid; f < NT*KT*64; f += 256) {
        int tile = f >> 6, l = f & 63;
        int nt = tile / KT, kt = tile - nt*KT;
        int col = q0 + nt*16 + (l & 15);
        int kb  = kt*16 + ((l >> 4) << 2);
        unsigned h[4];
#pragma unroll
        for (int i = 0; i < 4; ++i) {
            int pk_ = kb + i;
            int jr = pk_ / 66, rr = pk_ - jr*66;
            unsigned hv = 0;
            if (rr < 65 && col < QP) {
                int qrow = jr*65 + rr;
                unsigned w = AMATh[(size_t)qrow*260 + (col >> 1)];
                hv = (col & 1) ? (w >> 16) : (w & 0xffffu);
            }
            h[i] = hv;
        }
        uint2 pk;
        pk.x = h[0] | (h[1] << 16);
        pk.y = h[2] | (h[3] << 16);
        frag[f] = pk;
    }
    for (int i = tid; i < 16*(USTR/2); i += 256) ((unsigned*)ustage)[i] = 0u;
    __syncthreads();

    // ---- per-thread maps ----
    const int ntn = (wv == 0) ? 2 : 1;
    const int nts0 = wv;
    int eoff[2][4];
#pragma unroll
    for (int sl = 0; sl < 2; ++sl) {
#pragma unroll
        for (int r = 0; r < 4; ++r) {
            int nt  = sl ? 4 : nts0;
            int row = ((lane >> 4) << 2) + r;
            int col = nt*16 + (lane & 15);
            int q   = q0 + col;
            bool ok = (lane < 32) && (col < NSL) && (q < Qn) && (sl < ntn);
            eoff[sl][r] = ok ? ((b0 + row)*Qn + q) : -1;
        }
    }
    const int rrow = tid >> 5;     // reader row 0..7
    const int t32  = tid & 31;

    float llreg = 0.f;
    float v[17];
    float lsr = 0.f;

    // ---- t = 0 : u0 = max(E0,eps) * max(init,eps), tag 1, slot 0 ----
    {
        u64* fw = fbuf + ((size_t)0*NGRP + g)*8*QPW;
        for (int p = tid; p < 8*66; p += 256) {
            int row = p / 66, c = p - row*66;
            int q = q0 + c;
            float uv = 0.f;
            if (c < 65 && q < Qn)
                uv = fmaxf(E[(size_t)(b0+row)*Qn + q], EPSc) * fmaxf(INITD[q], EPSc);
            u64 pk = (u64)__builtin_bit_cast(unsigned, uv) | ((u64)1u << 32);
            __hip_atomic_store(&fw[(size_t)row*QPW + q0p + c], pk,
                               __ATOMIC_RELAXED, __HIP_MEMORY_SCOPE_AGENT);
        }
    }

    auto poll_read = [&](int s) {   // read data of step s-1 (tag s) from slot (s-1)&1
        const size_t base = ((size_t)((s-1) & 1)*NGRP + g)*8*QPW + (size_t)rrow*QPW;
        const u64* fb = fbuf + base;
        unsigned want = (unsigned)s;
        u64 w[17];
        unsigned pend = (t32 < 16) ? 0x1FFFFu : 0xFFFFu;
        while (true) {
#pragma unroll
            for (int k = 0; k < 17; ++k) {
                if (pend & (1u << k))
                    w[k] = __hip_atomic_load(&fb[t32 + 32*k],
                                             __ATOMIC_RELAXED, __HIP_MEMORY_SCOPE_AGENT);
            }
#pragma unroll
            for (int k = 0; k < 17; ++k)
                if ((pend & (1u << k)) && (unsigned)(w[k] >> 32) == want) pend &= ~(1u << k);
            if (pend == 0) break;
        }
        float sum = 0.f;
#pragma unroll
        for (int k = 0; k < 17; ++k) {
            int pc = t32 + 32*k;
            v[k] = (pc < QPW) ? __builtin_bit_cast(float, (unsigned)(w[k] & 0xffffffffu)) : 0.f;
            sum += v[k];
        }
#pragma unroll
        for (int o = 1; o < 32; o <<= 1) sum += __shfl_xor(sum, o);
        lsr = __logf(sum);
        llreg += lsr;
        return 1.f / sum;
    };

    auto emit_outputs = [&](int tOut) {
        if (j == 0 && t32 == 0)
            out[((size_t)(b0 + rrow)*Tn + tOut)*OQ + Qn] = llreg;
#pragma unroll
        for (int k = 0; k < 17; ++k) {
            int pc = t32 + 32*k;
            int c = pc - q0p;
            if (pc < QPW && c >= 0 && c < 65) {
                int q = q0 + c;
                if (q < Qn)
                    out[((size_t)(b0 + rrow)*Tn + tOut)*OQ + q] = __logf(v[k]) - lsr;
            }
        }
    };

    // ---- main loop ----
    for (int s = 1; s < Tn; ++s) {
        // prefetch E_s (latency hides under the poll)
        float ev[2][4];
        size_t ebase = (size_t)s * Bn * Qn;
#pragma unroll
        for (int sl = 0; sl < 2; ++sl)
#pragma unroll
            for (int r = 0; r < 4; ++r)
                ev[sl][r] = (eoff[sl][r] >= 0) ? E[ebase + eoff[sl][r]] : 0.f;

        float inv = poll_read(s);

        __syncthreads();   // all waves done with previous MFMA's ustage reads
#pragma unroll
        for (int k = 0; k < 17; ++k) {
            int pc = t32 + 32*k;
            if (pc < QPW)
                ustage[rrow*USTR + pc] = (unsigned short)bfbits(v[k] * inv);
        }
        __syncthreads();   // stage visible

        // MFMA: R = a_{s-1} (16xK, rows 8..15 zero) @ Aslice (KxN), split-K x2
        f32x4 a0a = {0.f,0.f,0.f,0.f}, a0b = {0.f,0.f,0.f,0.f};
        f32x4 a1a = {0.f,0.f,0.f,0.f}, a1b = {0.f,0.f,0.f,0.f};
        {
            const unsigned short* urow = ustage + (lane & 15)*USTR + ((lane >> 4) << 2);
            const uint2* f0 = frag + (size_t)(nts0*KT)*64 + lane;
            const uint2* f1 = frag + (size_t)(4*KT)*64 + lane;
#pragma unroll 2
            for (int kt = 0; kt < KTA; ++kt) {
                s16x4 af = __builtin_bit_cast(s16x4, *(const uint2*)(urow + kt*16));
                a0a = __builtin_amdgcn_mfma_f32_16x16x16bf16_1k(af, __builtin_bit_cast(s16x4, f0[kt*64]), a0a, 0, 0, 0);
                if (ntn == 2)
                    a1a = __builtin_amdgcn_mfma_f32_16x16x16bf16_1k(af, __builtin_bit_cast(s16x4, f1[kt*64]), a1a, 0, 0, 0);
                int k2 = kt + KTA;
                if (k2 < KT) {
                    s16x4 af2 = __builtin_bit_cast(s16x4, *(const uint2*)(urow + k2*16));
                    a0b = __builtin_amdgcn_mfma_f32_16x16x16bf16_1k(af2, __builtin_bit_cast(s16x4, f0[k2*64]), a0b, 0, 0, 0);
                    if (ntn == 2)
                        a1b = __builtin_amdgcn_mfma_f32_16x16x16bf16_1k(af2, __builtin_bit_cast(s16x4, f1[k2*64]), a1b, 0, 0, 0);
                }
            }
        }
        // epilogue: u_s = max(E,eps) * max(R,eps) -> tagged exchange stores (tag s+1, slot s&1)
        {
            unsigned seqv = (unsigned)(s + 1);
            u64* fw = fbuf + ((size_t)(s & 1)*NGRP + g)*8*QPW;
            if (lane < 32) {
#pragma unroll
                for (int r = 0; r < 4; ++r) {
                    int row = ((lane >> 4) << 2) + r;
                    {
                        int col = nts0*16 + (lane & 15);
                        float R = fmaxf(a0a[r] + a0b[r], EPSc);
                        int q = q0 + col;
                        float uv = (q < Qn) ? fmaxf(ev[0][r], EPSc) * R : 0.f;
                        u64 pk = (u64)__builtin_bit_cast(unsigned, uv) | ((u64)seqv << 32);
                        __hip_atomic_store(&fw[(size_t)row*QPW + q0p + col], pk,
                                           __ATOMIC_RELAXED, __HIP_MEMORY_SCOPE_AGENT);
                    }
                    if (ntn == 2 && (lane & 15) == 0) {
                        int col = 64;
                        float R = fmaxf(a1a[r] + a1b[r], EPSc);
                        int q = q0 + col;
                        float uv = (q < Qn) ? fmaxf(ev[1][r], EPSc) * R : 0.f;
                        u64 pk = (u64)__builtin_bit_cast(unsigned, uv) | ((u64)seqv << 32);
                        __hip_atomic_store(&fw[(size_t)row*QPW + q0p + col], pk,
                                           __ATOMIC_RELAXED, __HIP_MEMORY_SCOPE_AGENT);
                    }
                }
            }
            if (wv == 1 && lane >= 32 && lane < 40) {  // pad col 65 per row
                int row = lane - 32;
                u64 pk = ((u64)seqv << 32);
                __hip_atomic_store(&fw[(size_t)row*QPW + q0p + 65], pk,
                                   __ATOMIC_RELAXED, __HIP_MEMORY_SCOPE_AGENT);
            }
        }
        // off the critical path: log-outputs for t = s-1
        emit_outputs(s - 1);
    }

    // ---- tail: t = 511 ----
    poll_read(Tn);
    emit_outputs(Tn - 1);
}

extern "C" void kernel_launch(void* const* d_in, const int* in_sizes, int n_in,
                              void* d_out, int out_size, void* d_ws, size_t ws_size,
                              hipStream_t stream) {
    (void)in_sizes; (void)n_in; (void)out_size;
    if (ws_size < (size_t)WS_TOTAL) return;

    const float* E    = (const float*)d_in[0];
    const float* logA = (const float*)d_in[1];
    const float* il   = (const float*)d_in[2];
    float* out = (float*)d_out;
    char*  ws  = (char*)d_ws;

    unsigned* AMATh = (unsigned*)(ws + WS_AMATH);
    float*    INITD = (float*)(ws + WS_INIT);
    u64*      fbuf  = (u64*)(ws + WS_FBUF);

    prep_A<<<544, 256, 0, stream>>>(logA, AMATh);
    prep_init<<<1, 256, 0, stream>>>(il, INITD);

    static_assert(LDS_TOTAL < 160*1024, "LDS budget");
    hipFuncSetAttribute(reinterpret_cast<const void*>(hmm_fwd),
                        hipFuncAttributeMaxDynamicSharedMemorySize, LDS_TOTAL);
    hmm_fwd<<<256, 256, LDS_TOTAL, stream>>>(E, AMATh, INITD, out, fbuf);
}